// Round 1
// baseline (6217.915 us; speedup 1.0000x reference)
//
#include <hip/hip_runtime.h>
#include <math.h>

#define BB   4
#define SS   64
#define DD   512
#define HH   8
#define DHH  64
#define DFFF 2048
#define LL   2
#define VV   32128
#define TT   16
#define EPSV 1e-6f
#define NEGB (-1e9f)
#define GBLK 512
#define NTHR 256
#define NCH  502             // 502 * 64 = 32128 vocab columns
#define STS  512             // stride for per-chunk stat arrays

#define BSDc ((size_t)131072)    // B*S*D
#define DD2c ((size_t)262144)    // D*D
#define AGT  __HIP_MEMORY_SCOPE_AGENT

// ---------------- coherence-point (cache-bypass) access helpers -----------
__device__ __forceinline__ float gld(const float* p) {
    return __hip_atomic_load((float*)p, __ATOMIC_RELAXED, AGT);
}
__device__ __forceinline__ void gst(float* p, float v) {
    __hip_atomic_store(p, v, __ATOMIC_RELAXED, AGT);
}
__device__ __forceinline__ int gldi(const int* p) {
    return __hip_atomic_load((int*)p, __ATOMIC_RELAXED, AGT);
}
__device__ __forceinline__ void gsti(int* p, int v) {
    __hip_atomic_store(p, v, __ATOMIC_RELAXED, AGT);
}

// ---------------- 2-level relaxed tree barrier, templated on group count --
// layout (dwords, 128B line spacing): bar[0] root; bar[(1+g)*32] group ctr;
// bar[(1+NGRP+g)*32] group release flag (monotonic phase number).
// Blocks per group is fixed at 16 -> instance covers NGRP*16 blocks.
template<int NGRP>
__device__ __forceinline__ void bar_core_t(unsigned* bar, unsigned ph) {
    int g = blockIdx.x >> 4;
    unsigned* gc = bar + (size_t)(1 + g) * 32;
    unsigned* gf = bar + (size_t)(1 + NGRP + g) * 32;
    unsigned a = __hip_atomic_fetch_add(gc, 1u, __ATOMIC_RELAXED, AGT);
    if (a == 15u) {
        __hip_atomic_store(gc, 0u, __ATOMIC_RELAXED, AGT);
        __builtin_amdgcn_s_waitcnt(0);
        unsigned r = __hip_atomic_fetch_add(bar, 1u, __ATOMIC_RELAXED, AGT);
        if (r == (unsigned)(NGRP - 1)) {
            __hip_atomic_store(bar, 0u, __ATOMIC_RELAXED, AGT);
            __builtin_amdgcn_s_waitcnt(0);
            #pragma unroll
            for (int i = 0; i < NGRP; i++)
                __hip_atomic_store(bar + (size_t)(1 + NGRP + i) * 32, ph,
                                   __ATOMIC_RELAXED, AGT);
        }
    }
    while (__hip_atomic_load(gf, __ATOMIC_RELAXED, AGT) < ph)
        __builtin_amdgcn_s_sleep(2);
}
template<int NGRP>
__device__ __forceinline__ void gsync_nf_t(unsigned* bar, unsigned ph) {
    __builtin_amdgcn_s_waitcnt(0);
    __syncthreads();
    if (threadIdx.x == 0) bar_core_t<NGRP>(bar, ph);
    __syncthreads();
}
template<int NGRP>
__device__ __forceinline__ void gsync_f_t(unsigned* bar, unsigned ph) {
    __builtin_amdgcn_s_waitcnt(0);
    __syncthreads();
    if (threadIdx.x == 0) { __threadfence(); bar_core_t<NGRP>(bar, ph); __threadfence(); }
    __syncthreads();
}

// ---------------- row RMSNorm phase (encoder, blocks < 256) ---------------
__device__ void d_rms_row(const float* __restrict__ x, const float* __restrict__ ln,
                          float* __restrict__ h, float* sm) {
    int row = blockIdx.x, tid = threadIdx.x;
    const float* xr = x + (size_t)row * DD;
    float local = 0.f;
    for (int k = tid; k < DD; k += NTHR) { float v = xr[k]; local += v * v; }
    sm[tid] = local; __syncthreads();
    for (int s = 128; s > 0; s >>= 1) { if (tid < s) sm[tid] += sm[tid + s]; __syncthreads(); }
    float scale = 1.0f / sqrtf(sm[0] / DD + EPSV);
    __syncthreads();
    for (int k = tid; k < DD; k += NTHR) h[(size_t)row * DD + k] = xr[k] * scale * ln[k];
}

// ---------------- 64x64 GEMM tile (encoder) -------------------------------
__device__ void d_gemm_tile(const float* __restrict__ A, const float* __restrict__ W,
                            float* __restrict__ C, const float* __restrict__ res,
                            int K, int N, int relu, int tile, float* sm) {
    float* As = sm;                 // [16][65]
    float* Ws = sm + 16 * 65;       // [16][64]
    int tid = threadIdx.x;
    int tr = tid >> 4, tc = tid & 15;
    int nb = N >> 6;
    int row0 = (tile / nb) * 64, col0 = (tile % nb) * 64;
    float acc[4][4] = {};
    for (int k0 = 0; k0 < K; k0 += 16) {
        for (int i = tid; i < 64 * 16; i += NTHR) {
            int r = i >> 4, kk = i & 15;
            As[kk * 65 + r] = A[(size_t)(row0 + r) * K + k0 + kk];
        }
        for (int i = tid; i < 16 * 64; i += NTHR) {
            int kk = i >> 6, c = i & 63;
            Ws[kk * 64 + c] = W[(size_t)(k0 + kk) * N + col0 + c];
        }
        __syncthreads();
        #pragma unroll
        for (int kk = 0; kk < 16; kk++) {
            float a[4], b[4];
            #pragma unroll
            for (int j = 0; j < 4; j++) { a[j] = As[kk * 65 + tr * 4 + j]; b[j] = Ws[kk * 64 + tc * 4 + j]; }
            #pragma unroll
            for (int r = 0; r < 4; r++)
                #pragma unroll
                for (int c = 0; c < 4; c++) acc[r][c] += a[r] * b[c];
        }
        __syncthreads();
    }
    #pragma unroll
    for (int r = 0; r < 4; r++)
        #pragma unroll
        for (int c = 0; c < 4; c++) {
            int gr = row0 + tr * 4 + r, gc = col0 + tc * 4 + c;
            float v = acc[r][c];
            if (res) v += res[(size_t)gr * N + gc];
            if (relu) v = fmaxf(v, 0.f);
            C[(size_t)gr * N + gc] = v;
        }
}

// ---------------- encoder attention, job = (b,h) --------------------------
__device__ void d_enc_attn(const float* __restrict__ qkv, const float* __restrict__ mask,
                           float* __restrict__ o, int job, float* sm) {
    int b = job / HH, h = job % HH;
    int tid = threadIdx.x;
    int lane = tid & 63, wave = tid >> 6;
    float* qq = sm;
    float* kk = sm + 64 * 65;
    float* vv = sm + 2 * 64 * 65;
    for (int i = tid; i < SS * DHH; i += NTHR) {
        int s = i >> 6, d = i & 63;
        size_t src = (size_t)(b * SS + s) * DD + h * DHH + d;
        qq[s * 65 + d] = qkv[src];
        kk[s * 65 + d] = qkv[BSDc + src];
        vv[s * 65 + d] = qkv[2 * BSDc + src];
    }
    __syncthreads();
    float bias = (1.0f - mask[b * SS + lane]) * NEGB;
    for (int r = 0; r < 16; r++) {
        int s = wave * 16 + r;
        float sc = 0.f;
        for (int i = 0; i < DHH; i++) sc += qq[s * 65 + i] * kk[lane * 65 + i];
        sc = sc * 0.125f + bias;
        float m = sc;
        for (int o2 = 32; o2 > 0; o2 >>= 1) m = fmaxf(m, __shfl_xor(m, o2));
        float e = expf(sc - m);
        float sum = e;
        for (int o2 = 32; o2 > 0; o2 >>= 1) sum += __shfl_xor(sum, o2);
        float p = e / sum;
        float acc = 0.f;
        for (int t2 = 0; t2 < SS; t2++) acc += __shfl(p, t2) * vv[t2 * 65 + lane];
        o[(size_t)(b * SS + s) * DD + h * DHH + lane] = acc;
    }
    __syncthreads();
}

// ============ decoder building blocks (single-gld-pass, LDS-resident) =====

// load x (4 rows stride K) + optional two accumulators into hAT[k][4],
// then optional RMSNorm*ln in place. 1 gld pass over each input stream.
template<int K>
__device__ __forceinline__ void load_fold(const float* __restrict__ A,
                                          const float* __restrict__ a1,
                                          const float* __restrict__ a2,
                                          const float* __restrict__ ln,
                                          float* hAT, float* scl) {
    const int tid = threadIdx.x, lane = tid & 63, wv = tid >> 6;
    for (int k = tid; k < K; k += NTHR) {
        float4 r;
        r.x = gld(A + k);         r.y = gld(A + K + k);
        r.z = gld(A + 2 * K + k); r.w = gld(A + 3 * K + k);
        if (a1) {
            r.x += gld(a1 + k);         r.y += gld(a1 + K + k);
            r.z += gld(a1 + 2 * K + k); r.w += gld(a1 + 3 * K + k);
        }
        if (a2) {
            r.x += gld(a2 + k);         r.y += gld(a2 + K + k);
            r.z += gld(a2 + 2 * K + k); r.w += gld(a2 + 3 * K + k);
        }
        *(float4*)(hAT + (size_t)k * 4) = r;
    }
    __syncthreads();
    if (ln) {
        float loc = 0.f;
        for (int k = lane; k < K; k += 64) { float x = hAT[k * 4 + wv]; loc += x * x; }
        for (int o = 32; o > 0; o >>= 1) loc += __shfl_xor(loc, o);
        if (lane == 0) scl[wv] = 1.0f / sqrtf(loc / K + EPSV);
        __syncthreads();
        float s0 = scl[0], s1 = scl[1], s2 = scl[2], s3 = scl[3];
        for (int k = tid; k < K; k += NTHR) {
            float lw = ln[k];
            float4 r = *(float4*)(hAT + (size_t)k * 4);
            r.x *= s0 * lw; r.y *= s1 * lw; r.z *= s2 * lw; r.w *= s3 * lw;
            *(float4*)(hAT + (size_t)k * 4) = r;
        }
        __syncthreads();
    }
}

// small-M GEMV: hAT[K][4] (LDS) x W[K][N] cols [col0,col0+NC) -> outL[4][NC]
template<int K, int NC>
__device__ __forceinline__ void gemv_core(const float* hAT, const float* __restrict__ W,
                                          int N, int col0, float* red, float* outL) {
    constexpr int C4N = NC / 4;
    constexpr int KSN = NTHR / C4N;
    constexpr int KC  = K / KSN;
    const int tid = threadIdx.x;
    const int c4 = tid % C4N, ks = tid / C4N;
    const float4* W4 = (const float4*)W;
    float acc[4][4] = {};
    const int kb = ks * KC;
    #pragma unroll 8
    for (int kk = 0; kk < KC; kk++) {
        int k = kb + kk;
        float4 w4 = W4[(size_t)k * (N >> 2) + (col0 >> 2) + c4];
        float4 h4 = *(const float4*)(hAT + (size_t)k * 4);
        float hb[4] = {h4.x, h4.y, h4.z, h4.w};
        float wb[4] = {w4.x, w4.y, w4.z, w4.w};
        #pragma unroll
        for (int b = 0; b < 4; b++)
            #pragma unroll
            for (int ci = 0; ci < 4; ci++) acc[b][ci] += hb[b] * wb[ci];
    }
    {
        float* rp = red + (size_t)ks * (NC * 4) + c4 * 4;
        #pragma unroll
        for (int b = 0; b < 4; b++)
            #pragma unroll
            for (int ci = 0; ci < 4; ci++) rp[b * NC + ci] = acc[b][ci];
    }
    __syncthreads();
    for (int o = tid; o < 4 * NC; o += NTHR) {
        float v = 0.f;
        #pragma unroll
        for (int k2 = 0; k2 < KSN; k2++) v += red[(size_t)k2 * (NC * 4) + o];
        outL[o] = v;
    }
    __syncthreads();
}

// per-head output projection partial: accD[b][0..511] += att[b][c]*Wo[h*64+c][n]
__device__ __forceinline__ void oproj_add(const float* att, const float* __restrict__ Wo,
                                          int h, float* accD, float* red) {
    const int tid = threadIdx.x;
    const int n4 = tid & 127, cs = tid >> 7;
    const float4* Wo4 = (const float4*)Wo;
    float4 a0 = {0,0,0,0}, a1 = a0, a2 = a0, a3 = a0;
    #pragma unroll 8
    for (int cc = 0; cc < 32; cc++) {
        int c = cs * 32 + cc;
        float4 w4 = Wo4[(size_t)(h * 64 + c) * 128 + n4];
        float p0 = att[c], p1 = att[64 + c], p2 = att[128 + c], p3 = att[192 + c];
        a0.x += p0 * w4.x; a0.y += p0 * w4.y; a0.z += p0 * w4.z; a0.w += p0 * w4.w;
        a1.x += p1 * w4.x; a1.y += p1 * w4.y; a1.z += p1 * w4.z; a1.w += p1 * w4.w;
        a2.x += p2 * w4.x; a2.y += p2 * w4.y; a2.z += p2 * w4.z; a2.w += p2 * w4.w;
        a3.x += p3 * w4.x; a3.y += p3 * w4.y; a3.z += p3 * w4.z; a3.w += p3 * w4.w;
    }
    float4* red4 = (float4*)red;
    red4[(size_t)cs * 512 + n4 * 4 + 0] = a0;
    red4[(size_t)cs * 512 + n4 * 4 + 1] = a1;
    red4[(size_t)cs * 512 + n4 * 4 + 2] = a2;
    red4[(size_t)cs * 512 + n4 * 4 + 3] = a3;
    __syncthreads();
    for (int o0 = tid; o0 < 2048; o0 += NTHR) {
        int o = (o0 + h * 256) & 2047;               // h-stagger vs line contention
        int n = o & 511, b = o >> 9;
        int ri = ((n >> 2) << 4) + (b << 2) + (n & 3);
        atomicAdd(accD + o, red[ri] + red[2048 + ri]);
    }
    __syncthreads();
}

// fused decoder self-attn: RMS -> q/k/v head GEMVs -> attn -> o-proj partial
__device__ void d_self_f(const float* __restrict__ x0, const float* __restrict__ ln1,
                         const float* __restrict__ Wq, const float* __restrict__ Wk,
                         const float* __restrict__ Wv, const float* __restrict__ Wo,
                         float* __restrict__ sK, float* __restrict__ sV,
                         float* __restrict__ aS, int l, int tt, int h, float* sm) {
    float* hAT = sm;            // 2048
    float* red = sm + 2048;     // 4096
    float* qh  = sm + 6144;     // 256
    float* kh  = sm + 6400;     // 256
    float* vh  = sm + 6656;     // 256
    float* att = sm + 6912;     // 256
    float* scl = sm + 7168;     // 4
    const int tid = threadIdx.x, lane = tid & 63, wv = tid >> 6;

    load_fold<DD>(x0, nullptr, nullptr, ln1, hAT, scl);
    gemv_core<DD, 64>(hAT, Wq, DD, h * 64, red, qh);
    gemv_core<DD, 64>(hAT, Wk, DD, h * 64, red, kh);
    gemv_core<DD, 64>(hAT, Wv, DD, h * 64, red, vh);
    {   // KV-cache publish for future steps
        int b = tid >> 6, c = tid & 63;
        size_t dst = (((size_t)(l * BB + b)) * TT + tt) * DD + h * DHH + c;
        gst(sK + dst, kh[tid]);
        gst(sV + dst, vh[tid]);
    }
    // attention: wave = batch, lane = key position
    float sc = -1e30f;
    if (lane <= tt) {
        float s2 = 0.f;
        if (lane == tt) {
            #pragma unroll 16
            for (int i = 0; i < DHH; i++) s2 += qh[wv * 64 + i] * kh[wv * 64 + i];
        } else {
            const float* kr = sK + (((size_t)(l * BB + wv)) * TT + lane) * DD + h * DHH;
            #pragma unroll 16
            for (int i = 0; i < DHH; i++) s2 += qh[wv * 64 + i] * gld(kr + i);
        }
        sc = s2 * 0.125f;
    }
    float m = sc;
    for (int o2 = 32; o2 > 0; o2 >>= 1) m = fmaxf(m, __shfl_xor(m, o2));
    float e = (lane <= tt) ? expf(sc - m) : 0.f;
    float sum = e;
    for (int o2 = 32; o2 > 0; o2 >>= 1) sum += __shfl_xor(sum, o2);
    float pr = e / sum;
    float acc = 0.f;
    for (int j = 0; j < tt; j++) {
        float pj = __shfl(pr, j);
        acc += pj * gld(sV + (((size_t)(l * BB + wv)) * TT + j) * DD + h * DHH + lane);
    }
    acc += __shfl(pr, tt) * vh[wv * 64 + lane];
    att[wv * 64 + lane] = acc;
    __syncthreads();
    oproj_add(att, Wo, h, aS, red);
}

// fused decoder cross-attn: fold(x0+accS) -> RMS -> cq GEMV -> attn -> co partial
__device__ void d_cross_f(const float* __restrict__ x0, const float* __restrict__ aS,
                          const float* __restrict__ ln2, const float* __restrict__ Wq,
                          const float* __restrict__ Wo, const float* __restrict__ cK,
                          const float* __restrict__ cV, const float* __restrict__ mask,
                          float* __restrict__ aC, int l, int h, float* sm) {
    float* hAT = sm;
    float* red = sm + 2048;
    float* qh  = sm + 6144;
    float* att = sm + 6912;
    float* scl = sm + 7168;
    const int tid = threadIdx.x, lane = tid & 63, wv = tid >> 6;

    load_fold<DD>(x0, aS, nullptr, ln2, hAT, scl);
    gemv_core<DD, 64>(hAT, Wq, DD, h * 64, red, qh);
    // attention over the (immutable, cacheable) encoder K/V
    const float* kr = cK + (((size_t)(l * BB + wv)) * SS + lane) * DD + h * DHH;
    float s2 = 0.f;
    #pragma unroll 16
    for (int i = 0; i < DHH; i++) s2 += qh[wv * 64 + i] * kr[i];
    float sc = s2 * 0.125f + (1.0f - mask[wv * SS + lane]) * NEGB;
    float m = sc;
    for (int o2 = 32; o2 > 0; o2 >>= 1) m = fmaxf(m, __shfl_xor(m, o2));
    float e = expf(sc - m);
    float sum = e;
    for (int o2 = 32; o2 > 0; o2 >>= 1) sum += __shfl_xor(sum, o2);
    float pr = e / sum;
    float acc = 0.f;
    for (int j = 0; j < SS; j++) {
        float pj = __shfl(pr, j);
        acc += pj * cV[(((size_t)(l * BB + wv)) * SS + j) * DD + h * DHH + lane];
    }
    att[wv * 64 + lane] = acc;
    __syncthreads();
    oproj_add(att, Wo, h, aC, red);
}

// ===================== the mega-kernel ====================================
__global__ __launch_bounds__(NTHR, 2) void k_mega(
    const int* __restrict__ ids, const float* __restrict__ mask, const float* __restrict__ emb,
    const float* __restrict__ enc_wq, const float* __restrict__ enc_wk,
    const float* __restrict__ enc_wv, const float* __restrict__ enc_wo,
    const float* __restrict__ enc_ln1, const float* __restrict__ enc_w1,
    const float* __restrict__ enc_w2, const float* __restrict__ enc_ln2,
    const float* __restrict__ enc_lnf,
    const float* __restrict__ dec_sq, const float* __restrict__ dec_sk,
    const float* __restrict__ dec_sv, const float* __restrict__ dec_so,
    const float* __restrict__ dec_ln1,
    const float* __restrict__ dec_cq, const float* __restrict__ dec_ck,
    const float* __restrict__ dec_cv, const float* __restrict__ dec_co,
    const float* __restrict__ dec_ln2,
    const float* __restrict__ dec_w1, const float* __restrict__ dec_w2,
    const float* __restrict__ dec_ln3, const float* __restrict__ dec_lnf,
    const float* __restrict__ Wlm,
    float* __restrict__ out, float* __restrict__ wsb) {

    __shared__ float sm[12480];      // 48.75 KB
    unsigned* bar  = (unsigned*)wsb;     // 16 KB barrier region
    unsigned* barF = bar;                // 512-block barrier (32 groups)
    unsigned* barE = bar + 2080;         // 256-block barrier (16 groups, encoder)
    unsigned* barS = bar + 3136;         // 128-block barrier (8 groups, decode)
    unsigned* d9f  = bar + 3680;         // decode "state final" flag (per step)
    float* ws = wsb + 4096;

    float* xe    = ws;
    float* qkv   = xe + BSDc;
    float* hbuf  = qkv + 3 * BSDc;
    float* attb  = hbuf + BSDc;
    float* ffbuf = attb + BSDc;
    float* cK    = ffbuf + (size_t)BB * SS * DFFF;
    float* cV    = cK + LL * BSDc;
    float* sK    = cV + LL * BSDc;
    float* sV    = sK + (size_t)LL * BB * TT * DD;
    float* xdA   = sV + (size_t)LL * BB * TT * DD;   // 2048
    float* xdB   = xdA + 2048;
    float* dff   = xdB + 2048;               // 8192
    float* stm   = dff + 8192;               // [4][STS]
    float* sts   = stm + 4 * STS;
    int*   stix  = (int*)(sts + 4 * STS);
    float* accb  = sts + 4 * STS + 2048;     // accS[2] then accC[2], 8192 floats

    const int blk = blockIdx.x;
    const int tid = threadIdx.x;
    const int lane = tid & 63, wave = tid >> 6;
    unsigned phF = 0, phE = 0, phS = 0;
    #define GSNF() do { phF++; gsync_nf_t<32>(barF, phF); } while (0)
    #define GSE()  do { phE++; gsync_f_t<16>(barE, phE); } while (0)
    #define SB()   do { phS++; gsync_nf_t<8>(barS, phS); } while (0)

    if (blk < 256) {
        // ---------- E0: embedding gather + decoder-input init + acc zero ----
        {
            int id = ids[blk];
            const float* src = emb + (size_t)id * DD;
            float* dst = xe + (size_t)blk * DD;
            for (int k = tid; k < DD; k += NTHR) dst[k] = src[k];
            if (blk < BB) {
                float* xdp = xdA + (size_t)blk * DD;
                for (int k = tid; k < DD; k += NTHR) xdp[k] = emb[k];   // emb[PAD=0]
            }
            if (blk == 4)
                for (int k = tid; k < 8192; k += NTHR) gst(accb + k, 0.f);
        }
        GSE();

        // ---------- encoder layers (fenced 256-block barriers) ----------
        for (int l = 0; l < LL; l++) {
            d_rms_row(xe, enc_ln1 + (size_t)l * DD, hbuf, sm);
            GSE();
            if (blk < 96) {
                int m = blk >> 5, t2 = blk & 31;
                const float* W = (m == 0 ? enc_wq : (m == 1 ? enc_wk : enc_wv)) + (size_t)l * DD2c;
                d_gemm_tile(hbuf, W, qkv + (size_t)m * BSDc, nullptr, 512, 512, 0, t2, sm);
            }
            GSE();
            if (blk < 32) d_enc_attn(qkv, mask, attb, blk, sm);
            GSE();
            if (blk < 32) d_gemm_tile(attb, enc_wo + (size_t)l * DD2c, xe, xe, 512, 512, 0, blk, sm);
            GSE();
            d_rms_row(xe, enc_ln2 + (size_t)l * DD, hbuf, sm);
            GSE();
            if (blk < 128) d_gemm_tile(hbuf, enc_w1 + (size_t)l * DD * DFFF, ffbuf, nullptr, 512, 2048, 1, blk, sm);
            GSE();
            if (blk < 32) d_gemm_tile(ffbuf, enc_w2 + (size_t)l * DFFF * DD, xe, xe, 2048, 512, 0, blk, sm);
            GSE();
        }
        d_rms_row(xe, enc_lnf, hbuf, sm);
        GSE();
        if (blk < 128) {
            int m = blk >> 5, t2 = blk & 31;
            const float* W = (m < 2) ? (dec_ck + (size_t)m * DD2c) : (dec_cv + (size_t)(m - 2) * DD2c);
            float* O = (m < 2) ? (cK + (size_t)m * BSDc) : (cV + (size_t)(m - 2) * BSDc);
            d_gemm_tile(hbuf, W, O, nullptr, 512, 512, 0, t2, sm);
        }
        GSE();   // publishes cK/cV/xdA; decode is fence-free
    }

    // ---------- decode loop ----------
    for (int tt = 0; tt < TT; tt++) {
        float* xc = (tt & 1) ? xdB : xdA;      // current decoder state
        float* xn = (tt & 1) ? xdA : xdB;      // next (accumulated in D10)

        if (blk < 128) {
            for (int l = 0; l < LL; l++) {
                float* aS = accb + (size_t)l * 2048;
                float* aC = accb + 4096 + (size_t)l * 2048;
                // F1: fused self-attn pipeline — 8 blocks (one per head)
                if (blk < 8)
                    d_self_f(xc, dec_ln1 + (size_t)l * DD,
                             dec_sq + (size_t)l * DD2c, dec_sk + (size_t)l * DD2c,
                             dec_sv + (size_t)l * DD2c, dec_so + (size_t)l * DD2c,
                             sK, sV, aS, l, tt, blk, sm);
                SB();
                // F2: fused cross-attn pipeline — 8 blocks
                if (blk < 8)
                    d_cross_f(xc, aS, dec_ln2 + (size_t)l * DD,
                              dec_cq + (size_t)l * DD2c, dec_co + (size_t)l * DD2c,
                              cK, cV, mask, aC, l, blk, sm);
                SB();
                // F3: FFN up + relu — 128 blocks, folds x+accS+accC
                {
                    float* hAT = sm; float* red = sm + 2048;
                    float* outL = sm + 6144; float* scl = sm + 6208;
                    load_fold<DD>(xc, aS, aC, dec_ln3 + (size_t)l * DD, hAT, scl);
                    gemv_core<DD, 16>(hAT, dec_w1 + (size_t)l * DD * DFFF, DFFF, blk * 16, red, outL);
                    int col0 = blk * 16;
                    for (int o = tid; o < 64; o += NTHR) {
                        int b = o >> 4, c = o & 15;
                        gst(dff + (size_t)b * DFFF + col0 + c, fmaxf(outL[o], 0.f));
                    }
                }
                SB();
                // F4: FFN down + residual(x+accS+accC) -> xc (disjoint cols)
                if (blk < 64) {
                    float* hAT = sm; float* red = sm + 8192;
                    float* outL = sm + 12288; float* scl = sm + 12352;
                    load_fold<DFFF>(dff, nullptr, nullptr, nullptr, hAT, scl);
                    gemv_core<DFFF, 8>(hAT, dec_w2 + (size_t)l * DFFF * DD, DD, blk * 8, red, outL);
                    int col0 = blk * 8;
                    for (int o = tid; o < 32; o += NTHR) {
                        int b = o >> 3, c = o & 7;
                        size_t ix = (size_t)b * DD + col0 + c;
                        float v = outL[o] + gld(xc + ix) + gld(aS + ix) + gld(aC + ix);
                        gst(xc + ix, v);
                    }
                }
                SB();
            }
            if (blk == 0 && tid == 0)
                __hip_atomic_store(d9f, (unsigned)(tt + 1), __ATOMIC_RELAXED, AGT);
        } else {
            // blocks 128..511 join only for lm_head/merge
            if (tid == 0) {
                while (__hip_atomic_load(d9f, __ATOMIC_RELAXED, AGT) < (unsigned)(tt + 1))
                    __builtin_amdgcn_s_sleep(8);
            }
            __syncthreads();
        }

        // ---------- D9: lm_head (64 cols/block) + local softmax stats ----------
        {
            float* hAT = sm;            // 2048
            float* red = sm + 2048;     // 4096
            float* msc = sm + 6144;     // 4
            float* lgl = sm + 12224;    // 256 (persists to D10)
            if (blk < NCH) {
                for (int k = tid; k < DD; k += NTHR) {
                    float4 r;
                    r.x = gld(xc + k);          r.y = gld(xc + DD + k);
                    r.z = gld(xc + 2 * DD + k); r.w = gld(xc + 3 * DD + k);
                    *(float4*)(hAT + (size_t)k * 4) = r;
                }
                __syncthreads();
                {
                    float loc = 0.f;
                    for (int k = lane; k < DD; k += 64) { float x = hAT[k * 4 + wave]; loc += x * x; }
                    for (int o = 32; o > 0; o >>= 1) loc += __shfl_xor(loc, o);
                    if (lane == 0) msc[wave] = 1.0f / sqrtf(loc / DD + EPSV);
                }
                __syncthreads();
                float s0 = msc[0], s1 = msc[1], s2 = msc[2], s3 = msc[3];
                for (int k = tid; k < DD; k += NTHR) {
                    float lw = dec_lnf[k];
                    float4 r = *(float4*)(hAT + (size_t)k * 4);
                    r.x *= s0 * lw; r.y *= s1 * lw; r.z *= s2 * lw; r.w *= s3 * lw;
                    *(float4*)(hAT + (size_t)k * 4) = r;
                }
                __syncthreads();
                {   // lm_head GEMV: 64 cols, 16 c4-threads x 16 k-slices of 32
                    int c4 = tid & 15, ks = tid >> 4;
                    const float4* W4 = (const float4*)Wlm;
                    float acc[4][4] = {};
                    int kb = ks * 32;
                    #pragma unroll
                    for (int kk = 0; kk < 32; kk++) {
                        int k = kb + kk;
                        float4 w4 = W4[(size_t)k * (VV >> 2) + blk * 16 + c4];
                        float4 h4 = *(float4*)(hAT + (size_t)k * 4);
                        float hb[4] = {h4.x, h4.y, h4.z, h4.w};
                        float wb[4] = {w4.x, w4.y, w4.z, w4.w};
                        #pragma unroll
                        for (int b = 0; b < 4; b++)
                            #pragma unroll
                            for (int ci = 0; ci < 4; ci++) acc[b][ci] += hb[b] * wb[ci];
                    }
                    float* rp = red + ks * 256 + c4 * 4;
                    #pragma unroll
                    for (int b = 0; b < 4; b++)
                        #pragma unroll
                        for (int ci = 0; ci < 4; ci++) rp[b * 64 + ci] = acc[b][ci];
                }
                __syncthreads();
                {   // logits into LDS (persist): lgl[b*64 + c]
                    float v = 0.f;
                    #pragma unroll
                    for (int k2 = 0; k2 < 16; k2++) v += red[k2 * 256 + tid];
                    lgl[tid] = v;
                }
                __syncthreads();
                {   // per-chunk max/argmax/sum, wave b over its 64 cols
                    int b = wave;
                    float v0 = lgl[b * 64 + lane];
                    float mx = v0; int ix = lane;
                    for (int o = 32; o > 0; o >>= 1) {
                        float om = __shfl_xor(mx, o); int oi = __shfl_xor(ix, o);
                        if (om > mx || (om == mx && oi < ix)) { mx = om; ix = oi; }
                    }
                    float s = expf(v0 - mx);
                    for (int o = 32; o > 0; o >>= 1) s += __shfl_xor(s, o);
                    if (lane == 0) {
                        gst(stm + b * STS + blk, mx);
                        gst(sts + b * STS + blk, s);
                        gsti(stix + b * STS + blk, blk * 64 + ix);
                    }
                }
            } else if (blk == 511) {
                // zero next-state accumulator + per-layer attn accumulators
                for (int k = tid; k < 2048; k += NTHR) gst(xn + k, 0.f);
                for (int k = tid; k < 8192; k += NTHR) gst(accb + k, 0.f);
            }
        }
        GSNF();

        // ---------- D10: global merge + probs + emb (atomicAdd -> xn) ----------
        {
            float* mM  = sm + 6144;        // M[4], S[4]
            int*   jS  = (int*)(sm + 6152);
            float* pT  = sm + 6400;        // [64][4]
            float* red = sm + 2048;        // 4096
            float* lgl = sm + 12224;       // persisted logits
            {   // merge per b (wave b), all blocks
                int b = wave;
                float M = -1e30f, S = 0.f; int jb = 0;
                for (int j = lane; j < NCH; j += 64) {
                    float mj = gld(stm + b * STS + j), sj = gld(sts + b * STS + j);
                    if (mj > M) { S = S * expf(M - mj) + sj; M = mj; jb = j; }
                    else        { S += sj * expf(mj - M); }
                }
                for (int o = 32; o > 0; o >>= 1) {
                    float Mo = __shfl_xor(M, o), So = __shfl_xor(S, o);
                    int jo = __shfl_xor(jb, o);
                    if (Mo > M || (Mo == M && jo < jb)) { S = S * expf(M - Mo) + So; M = Mo; jb = jo; }
                    else { S += So * expf(Mo - M); }
                }
                if (lane == 0) { mM[b] = M; mM[4 + b] = S; jS[b] = jb; }
            }
            __syncthreads();
            if (blk < NCH) {
                {   // final probs for this chunk: write out + stash transposed
                    int b = tid >> 6, c = tid & 63;
                    float p = expf(lgl[tid] - mM[b]) / mM[4 + b];
                    out[((size_t)b * TT + tt) * VV + blk * 64 + c] = p;
                    pT[c * 4 + b] = p;
                }
                __syncthreads();
                {   // emb chunk (same 64 vocab rows as this block's logits!)
                    int c4 = tid & 127, rs = tid >> 7;
                    const float4* E4 = (const float4*)emb;
                    float4 a0 = {0,0,0,0}, a1 = a0, a2 = a0, a3 = a0;
                    int rb = rs * 32;
                    #pragma unroll 8
                    for (int r = 0; r < 32; r++) {
                        int row = rb + r;
                        float4 e4 = E4[((size_t)(blk * 64 + row)) * 128 + c4];
                        float4 p4 = *(float4*)(pT + row * 4);
                        a0.x += p4.x * e4.x; a0.y += p4.x * e4.y; a0.z += p4.x * e4.z; a0.w += p4.x * e4.w;
                        a1.x += p4.y * e4.x; a1.y += p4.y * e4.y; a1.z += p4.y * e4.z; a1.w += p4.y * e4.w;
                        a2.x += p4.z * e4.x; a2.y += p4.z * e4.y; a2.z += p4.z * e4.z; a2.w += p4.z * e4.w;
                        a3.x += p4.w * e4.x; a3.y += p4.w * e4.y; a3.z += p4.w * e4.z; a3.w += p4.w * e4.w;
                    }
                    float* rp = red + rs * 2048 + c4 * 4;
                    rp[0]        = a0.x; rp[1]        = a0.y; rp[2]        = a0.z; rp[3]        = a0.w;
                    rp[512 + 0]  = a1.x; rp[512 + 1]  = a1.y; rp[512 + 2]  = a1.z; rp[512 + 3]  = a1.w;
                    rp[1024 + 0] = a2.x; rp[1024 + 1] = a2.y; rp[1024 + 2] = a2.z; rp[1024 + 3] = a2.w;
                    rp[1536 + 0] = a3.x; rp[1536 + 1] = a3.y; rp[1536 + 2] = a3.z; rp[1536 + 3] = a3.w;
                }
                __syncthreads();
                #pragma unroll
                for (int i = 0; i < 8; i++) {
                    int o = tid + i * 256;
                    atomicAdd(xn + o, red[o] + red[2048 + o]);
                }
            }
            if (blk == 511 && tid < 4) {   // pred flags
                int col = gldi(stix + tid * STS + jS[tid]);
                out[(size_t)BB * TT * VV + tid * TT + tt] = (col == 0) ? 1.0f : 0.0f;
            }
            __syncthreads();
        }
        GSNF();
    }
    #undef GSNF
    #undef GSE
    #undef SB
}

extern "C" void kernel_launch(void* const* d_in, const int* in_sizes, int n_in,
                              void* d_out, int out_size, void* d_ws, size_t ws_size,
                              hipStream_t stream) {
    const int*   ids     = (const int*)  d_in[0];
    const float* mask    = (const float*)d_in[1];
    const float* emb     = (const float*)d_in[2];
    const float* enc_wq  = (const float*)d_in[3];
    const float* enc_wk  = (const float*)d_in[4];
    const float* enc_wv  = (const float*)d_in[5];
    const float* enc_wo  = (const float*)d_in[6];
    const float* enc_ln1 = (const float*)d_in[7];
    const float* enc_w1  = (const float*)d_in[8];
    const float* enc_w2  = (const float*)d_in[9];
    const float* enc_ln2 = (const float*)d_in[10];
    const float* enc_lnf = (const float*)d_in[11];
    const float* dec_sq  = (const float*)d_in[12];
    const float* dec_sk  = (const float*)d_in[13];
    const float* dec_sv  = (const float*)d_in[14];
    const float* dec_so  = (const float*)d_in[15];
    const float* dec_ln1 = (const float*)d_in[16];
    const float* dec_cq  = (const float*)d_in[17];
    const float* dec_ck  = (const float*)d_in[18];
    const float* dec_cv  = (const float*)d_in[19];
    const float* dec_co  = (const float*)d_in[20];
    const float* dec_ln2 = (const float*)d_in[21];
    const float* dec_w1  = (const float*)d_in[22];
    const float* dec_w2  = (const float*)d_in[23];
    const float* dec_ln3 = (const float*)d_in[24];
    const float* dec_lnf = (const float*)d_in[25];
    const float* lm_head = (const float*)d_in[26];

    hipMemsetAsync(d_ws, 0, 16384, stream);

    k_mega<<<GBLK, NTHR, 0, stream>>>(
        ids, mask, emb,
        enc_wq, enc_wk, enc_wv, enc_wo, enc_ln1, enc_w1, enc_w2, enc_ln2, enc_lnf,
        dec_sq, dec_sk, dec_sv, dec_so, dec_ln1,
        dec_cq, dec_ck, dec_cv, dec_co, dec_ln2,
        dec_w1, dec_w2, dec_ln3, dec_lnf, lm_head,
        (float*)d_out, (float*)d_ws);
}

// Round 2
// 3974.923 us; speedup vs baseline: 1.5643x; 1.5643x over previous
//
#include <hip/hip_runtime.h>
#include <math.h>

#define BB   4
#define SS   64
#define DD   512
#define HH   8
#define DHH  64
#define DFFF 2048
#define LL   2
#define VV   32128
#define TT   16
#define EPSV 1e-6f
#define NEGB (-1e9f)
#define NTHR 256
#define NCH  502             // 502 * 64 = 32128 vocab columns
#define STS  512             // stride for per-chunk stat arrays

#define BSDc ((size_t)131072)    // B*S*D
#define DD2c ((size_t)262144)    // D*D

// ===================== encoder kernels ====================================

__global__ __launch_bounds__(NTHR) void k_embed(const int* __restrict__ ids,
        const float* __restrict__ emb, float* __restrict__ xe, float* __restrict__ xd) {
    int blk = blockIdx.x, tid = threadIdx.x;
    int id = ids[blk];
    const float* src = emb + (size_t)id * DD;
    float* dst = xe + (size_t)blk * DD;
    for (int k = tid; k < DD; k += NTHR) dst[k] = src[k];
    if (blk < BB) {
        float* xdp = xd + (size_t)blk * DD;
        for (int k = tid; k < DD; k += NTHR) xdp[k] = emb[k];   // emb[PAD=0]
    }
}

__global__ __launch_bounds__(NTHR) void k_rms(const float* __restrict__ x,
        const float* __restrict__ ln, float* __restrict__ h) {
    __shared__ float sm[NTHR];
    int row = blockIdx.x, tid = threadIdx.x;
    const float* xr = x + (size_t)row * DD;
    float local = 0.f;
    for (int k = tid; k < DD; k += NTHR) { float v = xr[k]; local += v * v; }
    sm[tid] = local; __syncthreads();
    for (int s = 128; s > 0; s >>= 1) { if (tid < s) sm[tid] += sm[tid + s]; __syncthreads(); }
    float scale = 1.0f / sqrtf(sm[0] / DD + EPSV);
    for (int k = tid; k < DD; k += NTHR) h[(size_t)row * DD + k] = xr[k] * scale * ln[k];
}

// 64x64 GEMM tile; A is [256 x K], W is [K x N]
__device__ __forceinline__ void d_gemm_tile(const float* __restrict__ A, const float* __restrict__ W,
        float* __restrict__ C, const float* __restrict__ res,
        int K, int N, int relu, int tile, float* sm) {
    float* As = sm;                 // [16][65]
    float* Ws = sm + 16 * 65;       // [16][64]
    int tid = threadIdx.x;
    int tr = tid >> 4, tc = tid & 15;
    int nb = N >> 6;
    int row0 = (tile / nb) * 64, col0 = (tile % nb) * 64;
    float acc[4][4] = {};
    for (int k0 = 0; k0 < K; k0 += 16) {
        for (int i = tid; i < 64 * 16; i += NTHR) {
            int r = i >> 4, kk = i & 15;
            As[kk * 65 + r] = A[(size_t)(row0 + r) * K + k0 + kk];
        }
        for (int i = tid; i < 16 * 64; i += NTHR) {
            int kk = i >> 6, c = i & 63;
            Ws[kk * 64 + c] = W[(size_t)(k0 + kk) * N + col0 + c];
        }
        __syncthreads();
        #pragma unroll
        for (int kk = 0; kk < 16; kk++) {
            float a[4], b[4];
            #pragma unroll
            for (int j = 0; j < 4; j++) { a[j] = As[kk * 65 + tr * 4 + j]; b[j] = Ws[kk * 64 + tc * 4 + j]; }
            #pragma unroll
            for (int r = 0; r < 4; r++)
                #pragma unroll
                for (int c = 0; c < 4; c++) acc[r][c] += a[r] * b[c];
        }
        __syncthreads();
    }
    #pragma unroll
    for (int r = 0; r < 4; r++)
        #pragma unroll
        for (int c = 0; c < 4; c++) {
            int gr = row0 + tr * 4 + r, gc = col0 + tc * 4 + c;
            float v = acc[r][c];
            if (res) v += res[(size_t)gr * N + gc];
            if (relu) v = fmaxf(v, 0.f);
            C[(size_t)gr * N + gc] = v;
        }
}

__global__ __launch_bounds__(NTHR) void k_gemm(const float* __restrict__ A, const float* __restrict__ W,
        float* __restrict__ C, const float* __restrict__ res, int K, int N, int relu) {
    __shared__ float sm[16 * 65 + 16 * 64];
    d_gemm_tile(A, W, C, res, K, N, relu, blockIdx.x, sm);
}

__global__ __launch_bounds__(NTHR) void k_qkv(const float* __restrict__ A,
        const float* __restrict__ wq, const float* __restrict__ wk, const float* __restrict__ wv,
        float* __restrict__ qkv) {
    __shared__ float sm[16 * 65 + 16 * 64];
    int m = blockIdx.x >> 5, t2 = blockIdx.x & 31;
    const float* W = (m == 0) ? wq : (m == 1 ? wk : wv);
    d_gemm_tile(A, W, qkv + (size_t)m * BSDc, nullptr, 512, 512, 0, t2, sm);
}

__global__ __launch_bounds__(NTHR) void k_ckcv(const float* __restrict__ A,
        const float* __restrict__ wck, const float* __restrict__ wcv,
        float* __restrict__ cK, float* __restrict__ cV) {
    __shared__ float sm[16 * 65 + 16 * 64];
    int m = blockIdx.x >> 5, t2 = blockIdx.x & 31;
    const float* W = (m < 2) ? (wck + (size_t)m * DD2c) : (wcv + (size_t)(m - 2) * DD2c);
    float* O = (m < 2) ? (cK + (size_t)m * BSDc) : (cV + (size_t)(m - 2) * BSDc);
    d_gemm_tile(A, W, O, nullptr, 512, 512, 0, t2, sm);
}

__global__ __launch_bounds__(NTHR) void k_eattn(const float* __restrict__ qkv,
        const float* __restrict__ mask, float* __restrict__ o) {
    __shared__ float sm[3 * 64 * 65];
    int job = blockIdx.x;
    int b = job / HH, h = job % HH;
    int tid = threadIdx.x;
    int lane = tid & 63, wave = tid >> 6;
    float* qq = sm;
    float* kk = sm + 64 * 65;
    float* vv = sm + 2 * 64 * 65;
    for (int i = tid; i < SS * DHH; i += NTHR) {
        int s = i >> 6, d = i & 63;
        size_t src = (size_t)(b * SS + s) * DD + h * DHH + d;
        qq[s * 65 + d] = qkv[src];
        kk[s * 65 + d] = qkv[BSDc + src];
        vv[s * 65 + d] = qkv[2 * BSDc + src];
    }
    __syncthreads();
    float bias = (1.0f - mask[b * SS + lane]) * NEGB;
    for (int r = 0; r < 16; r++) {
        int s = wave * 16 + r;
        float sc = 0.f;
        for (int i = 0; i < DHH; i++) sc += qq[s * 65 + i] * kk[lane * 65 + i];
        sc = sc * 0.125f + bias;
        float m = sc;
        for (int o2 = 32; o2 > 0; o2 >>= 1) m = fmaxf(m, __shfl_xor(m, o2));
        float e = expf(sc - m);
        float sum = e;
        for (int o2 = 32; o2 > 0; o2 >>= 1) sum += __shfl_xor(sum, o2);
        float p = e / sum;
        float acc = 0.f;
        for (int t2 = 0; t2 < SS; t2++) acc += __shfl(p, t2) * vv[t2 * 65 + lane];
        o[(size_t)(b * SS + s) * DD + h * DHH + lane] = acc;
    }
}

// ===================== decode kernels =====================================

// small-M GEMV: optional RMSNorm(A rows)*ln -> hAT, then cols [cb*NC, +NC) of W
template<int K, int NC>
__device__ __forceinline__ void gemv_dev(const float* __restrict__ A, const float* __restrict__ ln,
        const float* __restrict__ W, float* __restrict__ O, int ostr, int N,
        const float* __restrict__ res, int relu, int cb, float* sm) {
    constexpr int C4N = NC / 4;            // float4 col-threads
    constexpr int KSN = NTHR / C4N;        // k-slices
    constexpr int KC  = K / KSN;           // k per slice
    const int tid = threadIdx.x, lane = tid & 63, wv = tid >> 6;
    float* hAT = sm;                       // K*4
    float* red = sm + K * 4;               // 4096
    float* scl = sm + K * 4 + 4096;        // 4
    if (ln) {
        const float* ar = A + (size_t)wv * K;
        float loc = 0.f;
        for (int k = lane; k < K; k += 64) { float x = ar[k]; loc += x * x; }
        for (int o = 32; o > 0; o >>= 1) loc += __shfl_xor(loc, o);
        if (lane == 0) scl[wv] = 1.0f / sqrtf(loc / K + EPSV);
    }
    __syncthreads();
    float s0 = ln ? scl[0] : 1.f, s1 = ln ? scl[1] : 1.f;
    float s2 = ln ? scl[2] : 1.f, s3 = ln ? scl[3] : 1.f;
    for (int k = tid; k < K; k += NTHR) {
        float lw = ln ? ln[k] : 1.0f;
        float4 h;
        h.x = A[k] * s0 * lw;
        h.y = A[K + k] * s1 * lw;
        h.z = A[2 * K + k] * s2 * lw;
        h.w = A[3 * K + k] * s3 * lw;
        *(float4*)(hAT + (size_t)k * 4) = h;
    }
    __syncthreads();
    const int c4 = tid % C4N, ks = tid / C4N;
    const float4* W4 = (const float4*)W;
    const int col0 = cb * NC;
    float acc[4][4] = {};
    const int kb = ks * KC;
    #pragma unroll 8
    for (int kk = 0; kk < KC; kk++) {
        int k = kb + kk;
        float4 w4 = W4[(size_t)k * (N >> 2) + (col0 >> 2) + c4];
        float4 h4 = *(float4*)(hAT + (size_t)k * 4);
        float hb[4] = {h4.x, h4.y, h4.z, h4.w};
        float wb[4] = {w4.x, w4.y, w4.z, w4.w};
        #pragma unroll
        for (int b = 0; b < 4; b++)
            #pragma unroll
            for (int ci = 0; ci < 4; ci++) acc[b][ci] += hb[b] * wb[ci];
    }
    {
        float* rp = red + (size_t)ks * (NC * 4) + c4 * 4;
        #pragma unroll
        for (int b = 0; b < 4; b++)
            #pragma unroll
            for (int ci = 0; ci < 4; ci++) rp[b * NC + ci] = acc[b][ci];
    }
    __syncthreads();
    for (int o = tid; o < 4 * NC; o += NTHR) {
        int b = o / NC, c = o % NC;
        float v = 0.f;
        #pragma unroll
        for (int k2 = 0; k2 < KSN; k2++) v += red[(size_t)k2 * (NC * 4) + o];
        if (res) v += res[(size_t)b * ostr + col0 + c];
        if (relu) v = fmaxf(v, 0.f);
        O[(size_t)b * ostr + col0 + c] = v;
    }
}

template<int K, int NC>
__global__ __launch_bounds__(NTHR) void k_gemv(const float* __restrict__ A, const float* __restrict__ ln,
        const float* __restrict__ W, float* __restrict__ O, int ostr, int N,
        const float* __restrict__ res, int relu) {
    __shared__ float sm[K * 4 + 4096 + 4];
    gemv_dev<K, NC>(A, ln, W, O, ostr, N, res, relu, blockIdx.x, sm);
}

__global__ __launch_bounds__(NTHR) void k_dqkv(const float* __restrict__ xc, const float* __restrict__ ln1,
        const float* __restrict__ wq, const float* __restrict__ wk, const float* __restrict__ wv,
        float* __restrict__ dq, float* __restrict__ sKw, float* __restrict__ sVw) {
    __shared__ float sm[512 * 4 + 4096 + 4];
    int m = blockIdx.x >> 5, cb = blockIdx.x & 31;
    const float* W = (m == 0) ? wq : (m == 1 ? wk : wv);
    float* O = (m == 0) ? dq : (m == 1 ? sKw : sVw);
    int ostr = (m == 0) ? DD : TT * DD;
    gemv_dev<512, 16>(xc, ln1, W, O, ostr, 512, nullptr, 0, cb, sm);
}

__global__ __launch_bounds__(NTHR) void k_dself(const float* __restrict__ dq,
        const float* __restrict__ sKl, const float* __restrict__ sVl,
        float* __restrict__ datt, int p) {
    __shared__ float qs[256];
    int h = blockIdx.x, tid = threadIdx.x, lane = tid & 63, b = tid >> 6;
    qs[b * 64 + lane] = dq[(size_t)b * DD + h * DHH + lane];
    __syncthreads();
    float sc = -1e30f;
    if (lane <= p) {
        const float* kr = sKl + ((size_t)b * TT + lane) * DD + h * DHH;
        float s2 = 0.f;
        #pragma unroll 16
        for (int i = 0; i < DHH; i++) s2 += qs[b * 64 + i] * kr[i];
        sc = s2 * 0.125f;
    }
    float m = sc;
    for (int o2 = 32; o2 > 0; o2 >>= 1) m = fmaxf(m, __shfl_xor(m, o2));
    float e = (lane <= p) ? expf(sc - m) : 0.f;
    float sum = e;
    for (int o2 = 32; o2 > 0; o2 >>= 1) sum += __shfl_xor(sum, o2);
    float pr = e / sum;
    float acc = 0.f;
    for (int j = 0; j <= p; j++) {
        float pj = __shfl(pr, j);
        acc += pj * sVl[((size_t)b * TT + j) * DD + h * DHH + lane];
    }
    datt[(size_t)b * DD + h * DHH + lane] = acc;
}

__global__ __launch_bounds__(NTHR) void k_dcross(const float* __restrict__ dq,
        const float* __restrict__ cKl, const float* __restrict__ cVl,
        const float* __restrict__ mask, float* __restrict__ datt) {
    __shared__ float qs[256];
    int h = blockIdx.x, tid = threadIdx.x, lane = tid & 63, b = tid >> 6;
    qs[b * 64 + lane] = dq[(size_t)b * DD + h * DHH + lane];
    __syncthreads();
    const float* kr = cKl + ((size_t)b * SS + lane) * DD + h * DHH;
    float s2 = 0.f;
    #pragma unroll 16
    for (int i = 0; i < DHH; i++) s2 += qs[b * 64 + i] * kr[i];
    float sc = s2 * 0.125f + (1.0f - mask[b * SS + lane]) * NEGB;
    float m = sc;
    for (int o2 = 32; o2 > 0; o2 >>= 1) m = fmaxf(m, __shfl_xor(m, o2));
    float e = expf(sc - m);
    float sum = e;
    for (int o2 = 32; o2 > 0; o2 >>= 1) sum += __shfl_xor(sum, o2);
    float pr = e / sum;
    float acc = 0.f;
    for (int j = 0; j < SS; j++) {
        float pj = __shfl(pr, j);
        acc += pj * cVl[((size_t)b * SS + j) * DD + h * DHH + lane];
    }
    datt[(size_t)b * DD + h * DHH + lane] = acc;
}

// lm_head chunk (blocks 0..501) + stats; block 502 zeroes next-state
__global__ __launch_bounds__(NTHR) void k_lmhead(const float* __restrict__ xc, float* __restrict__ xn,
        const float* __restrict__ lnf, const float* __restrict__ Wlm,
        float* __restrict__ lgb, float* __restrict__ stm, float* __restrict__ sts,
        int* __restrict__ stix) {
    int blk = blockIdx.x, tid = threadIdx.x, lane = tid & 63, wave = tid >> 6;
    if (blk >= NCH) {
        for (int k = tid; k < BB * DD; k += NTHR) xn[k] = 0.f;
        return;
    }
    __shared__ float hAT[2048];
    __shared__ float red[4096];
    __shared__ float msc[4];
    __shared__ float lgl[256];
    for (int k = tid; k < DD; k += NTHR) {
        float4 r;
        r.x = xc[k];          r.y = xc[DD + k];
        r.z = xc[2 * DD + k]; r.w = xc[3 * DD + k];
        *(float4*)(hAT + (size_t)k * 4) = r;
    }
    __syncthreads();
    {
        float loc = 0.f;
        for (int k = lane; k < DD; k += 64) { float x = hAT[k * 4 + wave]; loc += x * x; }
        for (int o = 32; o > 0; o >>= 1) loc += __shfl_xor(loc, o);
        if (lane == 0) msc[wave] = 1.0f / sqrtf(loc / DD + EPSV);
    }
    __syncthreads();
    float s0 = msc[0], s1 = msc[1], s2 = msc[2], s3 = msc[3];
    for (int k = tid; k < DD; k += NTHR) {
        float lw = lnf[k];
        float4 r = *(float4*)(hAT + (size_t)k * 4);
        r.x *= s0 * lw; r.y *= s1 * lw; r.z *= s2 * lw; r.w *= s3 * lw;
        *(float4*)(hAT + (size_t)k * 4) = r;
    }
    __syncthreads();
    {   // 64 cols, 16 c4-threads x 16 k-slices of 32
        int c4 = tid & 15, ks = tid >> 4;
        const float4* W4 = (const float4*)Wlm;
        float acc[4][4] = {};
        int kb = ks * 32;
        #pragma unroll
        for (int kk = 0; kk < 32; kk++) {
            int k = kb + kk;
            float4 w4 = W4[(size_t)k * (VV >> 2) + blk * 16 + c4];
            float4 h4 = *(float4*)(hAT + (size_t)k * 4);
            float hb[4] = {h4.x, h4.y, h4.z, h4.w};
            float wb[4] = {w4.x, w4.y, w4.z, w4.w};
            #pragma unroll
            for (int b = 0; b < 4; b++)
                #pragma unroll
                for (int ci = 0; ci < 4; ci++) acc[b][ci] += hb[b] * wb[ci];
        }
        float* rp = red + ks * 256 + c4 * 4;
        #pragma unroll
        for (int b = 0; b < 4; b++)
            #pragma unroll
            for (int ci = 0; ci < 4; ci++) rp[b * 64 + ci] = acc[b][ci];
    }
    __syncthreads();
    {
        float v = 0.f;
        #pragma unroll
        for (int k2 = 0; k2 < 16; k2++) v += red[k2 * 256 + tid];
        lgl[tid] = v;
        lgb[(size_t)(tid >> 6) * VV + blk * 64 + (tid & 63)] = v;
    }
    __syncthreads();
    {
        int b = wave;
        float v0 = lgl[b * 64 + lane];
        float mx = v0; int ix = lane;
        for (int o = 32; o > 0; o >>= 1) {
            float om = __shfl_xor(mx, o); int oi = __shfl_xor(ix, o);
            if (om > mx || (om == mx && oi < ix)) { mx = om; ix = oi; }
        }
        float s = expf(v0 - mx);
        for (int o = 32; o > 0; o >>= 1) s += __shfl_xor(s, o);
        if (lane == 0) {
            stm[b * STS + blk] = mx;
            sts[b * STS + blk] = s;
            stix[b * STS + blk] = blk * 64 + ix;
        }
    }
}

// merge stats + probs out + soft-emb partial -> xn; block 502 writes preds
__global__ __launch_bounds__(NTHR) void k_dmerge(const float* __restrict__ lgb,
        const float* __restrict__ stm, const float* __restrict__ sts, const int* __restrict__ stix,
        const float* __restrict__ emb, float* __restrict__ out, float* __restrict__ xn, int tt) {
    __shared__ float mM[8];
    __shared__ int jS[4];
    __shared__ float pT[256];
    __shared__ float red[4096];
    int blk = blockIdx.x, tid = threadIdx.x, lane = tid & 63, wave = tid >> 6;
    {   // merge per b (wave b)
        int b = wave;
        float M = -1e30f, S = 0.f; int jb = 0;
        for (int j = lane; j < NCH; j += 64) {
            float mj = stm[b * STS + j], sj = sts[b * STS + j];
            if (mj > M) { S = S * expf(M - mj) + sj; M = mj; jb = j; }
            else        { S += sj * expf(mj - M); }
        }
        for (int o = 32; o > 0; o >>= 1) {
            float Mo = __shfl_xor(M, o), So = __shfl_xor(S, o);
            int jo = __shfl_xor(jb, o);
            if (Mo > M || (Mo == M && jo < jb)) { S = S * expf(M - Mo) + So; M = Mo; jb = jo; }
            else { S += So * expf(Mo - M); }
        }
        if (lane == 0) { mM[b] = M; mM[4 + b] = S; jS[b] = jb; }
    }
    __syncthreads();
    if (blk < NCH) {
        {   // final probs for this chunk: write out + stash transposed
            int b = tid >> 6, c = tid & 63;
            float lg = lgb[(size_t)b * VV + blk * 64 + c];
            float p = expf(lg - mM[b]) / mM[4 + b];
            out[((size_t)b * TT + tt) * VV + blk * 64 + c] = p;
            pT[c * 4 + b] = p;
        }
        __syncthreads();
        {   // emb chunk (same 64 vocab rows as this block's logits)
            int c4 = tid & 127, rs = tid >> 7;
            const float4* E4 = (const float4*)emb;
            float4 a0 = {0,0,0,0}, a1 = a0, a2 = a0, a3 = a0;
            int rb = rs * 32;
            #pragma unroll 8
            for (int r = 0; r < 32; r++) {
                int row = rb + r;
                float4 e4 = E4[((size_t)(blk * 64 + row)) * 128 + c4];
                float4 p4 = *(float4*)(pT + row * 4);
                a0.x += p4.x * e4.x; a0.y += p4.x * e4.y; a0.z += p4.x * e4.z; a0.w += p4.x * e4.w;
                a1.x += p4.y * e4.x; a1.y += p4.y * e4.y; a1.z += p4.y * e4.z; a1.w += p4.y * e4.w;
                a2.x += p4.z * e4.x; a2.y += p4.z * e4.y; a2.z += p4.z * e4.z; a2.w += p4.z * e4.w;
                a3.x += p4.w * e4.x; a3.y += p4.w * e4.y; a3.z += p4.w * e4.z; a3.w += p4.w * e4.w;
            }
            float* rp = red + rs * 2048 + c4 * 4;
            rp[0]        = a0.x; rp[1]        = a0.y; rp[2]        = a0.z; rp[3]        = a0.w;
            rp[512 + 0]  = a1.x; rp[512 + 1]  = a1.y; rp[512 + 2]  = a1.z; rp[512 + 3]  = a1.w;
            rp[1024 + 0] = a2.x; rp[1024 + 1] = a2.y; rp[1024 + 2] = a2.z; rp[1024 + 3] = a2.w;
            rp[1536 + 0] = a3.x; rp[1536 + 1] = a3.y; rp[1536 + 2] = a3.z; rp[1536 + 3] = a3.w;
        }
        __syncthreads();
        #pragma unroll
        for (int i = 0; i < 8; i++) {
            int o = tid + i * 256;
            atomicAdd(xn + o, red[o] + red[2048 + o]);
        }
    } else {
        if (tid < 4) {   // pred flags
            int col = stix[tid * STS + jS[tid]];
            out[(size_t)BB * TT * VV + tid * TT + tt] = (col == 0) ? 1.0f : 0.0f;
        }
    }
}

// ===================== launch =============================================
extern "C" void kernel_launch(void* const* d_in, const int* in_sizes, int n_in,
                              void* d_out, int out_size, void* d_ws, size_t ws_size,
                              hipStream_t stream) {
    const int*   ids     = (const int*)  d_in[0];
    const float* mask    = (const float*)d_in[1];
    const float* emb     = (const float*)d_in[2];
    const float* enc_wq  = (const float*)d_in[3];
    const float* enc_wk  = (const float*)d_in[4];
    const float* enc_wv  = (const float*)d_in[5];
    const float* enc_wo  = (const float*)d_in[6];
    const float* enc_ln1 = (const float*)d_in[7];
    const float* enc_w1  = (const float*)d_in[8];
    const float* enc_w2  = (const float*)d_in[9];
    const float* enc_ln2 = (const float*)d_in[10];
    const float* enc_lnf = (const float*)d_in[11];
    const float* dec_sq  = (const float*)d_in[12];
    const float* dec_sk  = (const float*)d_in[13];
    const float* dec_sv  = (const float*)d_in[14];
    const float* dec_so  = (const float*)d_in[15];
    const float* dec_ln1 = (const float*)d_in[16];
    const float* dec_cq  = (const float*)d_in[17];
    const float* dec_ck  = (const float*)d_in[18];
    const float* dec_cv  = (const float*)d_in[19];
    const float* dec_co  = (const float*)d_in[20];
    const float* dec_ln2 = (const float*)d_in[21];
    const float* dec_w1  = (const float*)d_in[22];
    const float* dec_w2  = (const float*)d_in[23];
    const float* dec_ln3 = (const float*)d_in[24];
    const float* dec_lnf = (const float*)d_in[25];
    const float* lm_head = (const float*)d_in[26];
    float* out = (float*)d_out;

    // ---- workspace layout (floats) ----
    float* ws    = (float*)d_ws;
    float* xe    = ws;                                  // 131072
    float* qkv   = xe + BSDc;                           // 393216
    float* hbuf  = qkv + 3 * BSDc;                      // 131072
    float* attb  = hbuf + BSDc;                         // 131072
    float* ffbuf = attb + BSDc;                         // 524288
    float* cK    = ffbuf + (size_t)BB * SS * DFFF;      // 262144
    float* cV    = cK + LL * BSDc;                      // 262144
    float* sK    = cV + LL * BSDc;                      // 65536
    float* sV    = sK + (size_t)LL * BB * TT * DD;      // 65536
    float* xdA   = sV + (size_t)LL * BB * TT * DD;      // 2048
    float* xdB   = xdA + 2048;                          // 2048
    float* dq    = xdB + 2048;                          // 2048
    float* datt  = dq + 2048;                           // 2048
    float* dff   = datt + 2048;                         // 8192
    float* stm   = dff + 8192;                          // 2048
    float* sts   = stm + 4 * STS;                       // 2048
    int*   stix  = (int*)(sts + 4 * STS);               // 2048
    float* lgb   = (float*)(stix) + 2048;               // 128512 (4*VV)

    // ---------- encoder ----------
    k_embed<<<256, NTHR, 0, stream>>>(ids, emb, xe, xdA);
    for (int l = 0; l < LL; l++) {
        k_rms<<<256, NTHR, 0, stream>>>(xe, enc_ln1 + (size_t)l * DD, hbuf);
        k_qkv<<<96, NTHR, 0, stream>>>(hbuf, enc_wq + (size_t)l * DD2c,
                                       enc_wk + (size_t)l * DD2c, enc_wv + (size_t)l * DD2c, qkv);
        k_eattn<<<32, NTHR, 0, stream>>>(qkv, mask, attb);
        k_gemm<<<32, NTHR, 0, stream>>>(attb, enc_wo + (size_t)l * DD2c, xe, xe, 512, 512, 0);
        k_rms<<<256, NTHR, 0, stream>>>(xe, enc_ln2 + (size_t)l * DD, hbuf);
        k_gemm<<<128, NTHR, 0, stream>>>(hbuf, enc_w1 + (size_t)l * DD * DFFF, ffbuf, nullptr, 512, 2048, 1);
        k_gemm<<<32, NTHR, 0, stream>>>(ffbuf, enc_w2 + (size_t)l * DFFF * DD, xe, xe, 2048, 512, 0);
    }
    k_rms<<<256, NTHR, 0, stream>>>(xe, enc_lnf, hbuf);
    k_ckcv<<<128, NTHR, 0, stream>>>(hbuf, dec_ck, dec_cv, cK, cV);

    // ---------- decode ----------
    for (int tt = 0; tt < TT; tt++) {
        float* xc = (tt & 1) ? xdB : xdA;
        float* xn = (tt & 1) ? xdA : xdB;
        for (int l = 0; l < LL; l++) {
            k_dqkv<<<96, NTHR, 0, stream>>>(xc, dec_ln1 + (size_t)l * DD,
                    dec_sq + (size_t)l * DD2c, dec_sk + (size_t)l * DD2c, dec_sv + (size_t)l * DD2c,
                    dq, sK + ((size_t)l * BB * TT + tt) * DD, sV + ((size_t)l * BB * TT + tt) * DD);
            k_dself<<<8, NTHR, 0, stream>>>(dq, sK + (size_t)l * BB * TT * DD,
                    sV + (size_t)l * BB * TT * DD, datt, tt);
            k_gemv<512, 16><<<32, NTHR, 0, stream>>>(datt, nullptr, dec_so + (size_t)l * DD2c,
                    xc, DD, 512, xc, 0);
            k_gemv<512, 16><<<32, NTHR, 0, stream>>>(xc, dec_ln2 + (size_t)l * DD,
                    dec_cq + (size_t)l * DD2c, dq, DD, 512, nullptr, 0);
            k_dcross<<<8, NTHR, 0, stream>>>(dq, cK + (size_t)l * BSDc, cV + (size_t)l * BSDc, mask, datt);
            k_gemv<512, 16><<<32, NTHR, 0, stream>>>(datt, nullptr, dec_co + (size_t)l * DD2c,
                    xc, DD, 512, xc, 0);
            k_gemv<512, 16><<<128, NTHR, 0, stream>>>(xc, dec_ln3 + (size_t)l * DD,
                    dec_w1 + (size_t)l * DD * DFFF, dff, DFFF, DFFF, nullptr, 1);
            k_gemv<2048, 8><<<64, NTHR, 0, stream>>>(dff, nullptr, dec_w2 + (size_t)l * DFFF * DD,
                    xc, DD, 512, xc, 0);
        }
        k_lmhead<<<NCH + 1, NTHR, 0, stream>>>(xc, xn, dec_lnf, lm_head, lgb, stm, sts, stix);
        k_dmerge<<<NCH + 1, NTHR, 0, stream>>>(lgb, stm, sts, stix, emb, out, xn, tt);
    }
}